// Round 9
// baseline (19293.307 us; speedup 1.0000x reference)
//
#include <hip/hip_runtime.h>
#include <hip/hip_bf16.h>

// LSTMSeq2SeqModel: B=16, S=512, T=48, H=256, X=16, U=8. Output f32 (proven r6).
// Round 9: recurrence restructured. Old k_rec: 16 blocks/dir each re-streaming
// the full 1MB Whh from L2 every step -> per-CU L2 port bound (7.4us/step,
// measured 7.8). New k_recP: 32 blocks/dir, each owns 8 hidden units
// (32 rows x 256 = 32KB Whh, LDS-resident, loaded ONCE), computes its slice
// for ALL 16 batches; h exchanged per step via device-scope atomics on global
// hg[2] double buffer + spin grid barrier (64 blocks, co-resident).
//
// ws layout (floats) unchanged from r8 except pk* unused and:
//   hg   @ 12645376  [2][2][16][256]
//   sync @ 12661760  2 ints (cnt, gen), memset per k_recP launch

#define S_LEN 512
#define BATCH 16
#define T_LEN 48
#define WS_NEED_BYTES 93716480ull

__device__ __forceinline__ float sigm(float x) { return 1.f / (1.f + expf(-x)); }

__device__ __forceinline__ void gbar(int* cnt, int* gen, int nb, int target)
{
    __syncthreads();
    if (threadIdx.x == 0) {
        __threadfence();
        if (atomicAdd(cnt, 1) == nb - 1) {
            atomicExch(cnt, 0);
            atomicAdd(gen, 1);
        } else {
            while (atomicAdd(gen, 0) < target) __builtin_amdgcn_s_sleep(2);
        }
        __threadfence();
    }
    __syncthreads();
}

__global__ __launch_bounds__(256) void k_guard(float* __restrict__ outp,
                                               int out_size, float v)
{
    int idx = blockIdx.x * 256 + threadIdx.x;
    if (idx >= out_size) return;
    outp[idx] = (idx < 6144) ? v : 0.f;
}

__global__ __launch_bounds__(256) void k_inp(const float* __restrict__ x,
                                             const float* __restrict__ u,
                                             float* __restrict__ inp)
{
    int idx = blockIdx.x * 256 + threadIdx.x;
    if (idx >= 8192 * 24) return;
    int m = idx / 24, c = idx - m * 24;
    int t = m >> 4, b = m & 15;
    inp[idx] = (c < 16) ? x[((size_t)b * S_LEN + t) * 16 + c]
                        : u[((size_t)b * S_LEN + t) * 8 + (c - 16)];
}

__global__ __launch_bounds__(256) void k_pack4(const float* __restrict__ W,
                                               float* __restrict__ dst, int K)
{
    int idx = blockIdx.x * 256 + threadIdx.x;
    if (idx >= 1024 * K) return;
    int g = idx / K, k = idx - g * K;
    dst[(((k >> 2) * 1024 + g) << 2) + (k & 3)] = W[idx];
}

__global__ __launch_bounds__(256) void k_trT(const float* __restrict__ W, int ld,
                                             float* __restrict__ dst)
{
    int idx = blockIdx.x * 256 + threadIdx.x;   // 65536
    int n = idx >> 8, k = idx & 255;
    dst[k * 256 + n] = W[(size_t)n * ld + k];
}

__global__ __launch_bounds__(256) void k_trEp(const float* __restrict__ src,
                                              float* __restrict__ dst)
{
    int idx = blockIdx.x * 256 + threadIdx.x;   // 2097152
    int m = idx >> 8, k = idx & 255;
    int s = m >> 4, b = m & 15;
    dst[((size_t)(b * 256 + k) << 9) + s] = src[idx];
}

__global__ __launch_bounds__(256) void k_ngemm(
    const float* __restrict__ A, int lda,
    const float* __restrict__ B, int ldb,
    const float* __restrict__ bias1, const float* __restrict__ bias2,
    float* __restrict__ C, int M, int N, int K)
{
    int id = blockIdx.x * 256 + threadIdx.x;
    if (id >= M * N) return;
    int m = id / N, n = id - m * N;
    const float* a  = A + (size_t)m * lda;
    const float* br = B + (size_t)n * ldb;
    float s = bias1[n] + bias2[n];
#pragma unroll 8
    for (int k = 0; k < K; k++) s += a[k] * br[k];
    C[id] = s;
}

#define BM 64
#define BN 64
#define BK 16
__global__ __launch_bounds__(256) void k_gemm(
    const float* __restrict__ A, int lda,
    const float* __restrict__ B, int ldb, int bco,
    const float* __restrict__ bias1, const float* __restrict__ bias2,
    float* __restrict__ C, int N, int K)
{
    __shared__ float As[BK][BM + 4];
    __shared__ float Bs[BK][BN + 4];
    int tid = threadIdx.x;
    int m0 = blockIdx.x * BM, n0 = blockIdx.y * BN;
    int tx = tid & 15, ty = tid >> 4;
    float acc[4][4] = {};
    int lr = tid >> 2;
    int lk4 = (tid & 3) * 4;
    for (int k0 = 0; k0 < K; k0 += BK) {
        float4 av = *(const float4*)(A + (size_t)(m0 + lr) * lda + k0 + lk4);
        float4 bv = *(const float4*)(B + (size_t)(n0 + lr) * ldb + bco + k0 + lk4);
        As[lk4 + 0][lr] = av.x; As[lk4 + 1][lr] = av.y; As[lk4 + 2][lr] = av.z; As[lk4 + 3][lr] = av.w;
        Bs[lk4 + 0][lr] = bv.x; Bs[lk4 + 1][lr] = bv.y; Bs[lk4 + 2][lr] = bv.z; Bs[lk4 + 3][lr] = bv.w;
        __syncthreads();
#pragma unroll
        for (int k = 0; k < BK; k++) {
            const float4 a  = *(const float4*)&As[k][ty * 4];
            const float4 bq = *(const float4*)&Bs[k][tx * 4];
            acc[0][0] += a.x * bq.x; acc[0][1] += a.x * bq.y; acc[0][2] += a.x * bq.z; acc[0][3] += a.x * bq.w;
            acc[1][0] += a.y * bq.x; acc[1][1] += a.y * bq.y; acc[1][2] += a.y * bq.z; acc[1][3] += a.y * bq.w;
            acc[2][0] += a.z * bq.x; acc[2][1] += a.z * bq.y; acc[2][2] += a.z * bq.z; acc[2][3] += a.z * bq.w;
            acc[3][0] += a.w * bq.x; acc[3][1] += a.w * bq.y; acc[3][2] += a.w * bq.z; acc[3][3] += a.w * bq.w;
        }
        __syncthreads();
    }
    float bs[4];
#pragma unroll
    for (int jj = 0; jj < 4; jj++) {
        int n = n0 + tx * 4 + jj;
        bs[jj] = bias1[n] + (bias2 ? bias2[n] : 0.f);
    }
#pragma unroll
    for (int ii = 0; ii < 4; ii++) {
        float4 o = make_float4(acc[ii][0] + bs[0], acc[ii][1] + bs[1],
                               acc[ii][2] + bs[2], acc[ii][3] + bs[3]);
        *(float4*)(C + (size_t)(m0 + ty * 4 + ii) * N + n0 + tx * 4) = o;
    }
}

// ---------------- persistent recurrence: grid (32,2) x 1024, spin grid-barrier.
// Block (q,dir) owns units [q*8, q*8+8): 32 gate-rows x 256 cols in LDS.
// Thread roles: dot role (r=tid>>5 local row, b=(tid&31)>>1, kh=tid&1 k-half);
// cell role (tid<128): unit ju2=tid>>4, batch b2=tid&15 (c,h in registers).
__global__ __launch_bounds__(1024) void k_recP(
    const float* __restrict__ Gx,        // [2][8192][1024], biases folded
    const float* __restrict__ WhhF, const float* __restrict__ WhhB,
    float* __restrict__ y,               // [8192][512]
    float* hg,                           // [2][2][16][256] h exchange (atomics)
    int* syncp,                          // {cnt, gen}, zeroed before launch
    float* __restrict__ hbO, float* __restrict__ cbO)
{
    const int q = blockIdx.x;            // 0..31
    const int dir = blockIdx.y;
    const int tid = threadIdx.x;
    const int r = tid >> 5;              // 0..31
    const int rem = tid & 31;
    const int b = rem >> 1;              // 0..15
    const int kh = rem & 1;              // 0..1
    const int gt = r >> 3, ju = r & 7;
    const int grow = gt * 256 + q * 8 + ju;
    const float* W = dir ? WhhB : WhhF;
    const float* gx = Gx + (size_t)dir * 8388608;
    int* cnt = syncp;
    int* gen = syncp + 1;

    __shared__ float Ws[32][260];
    __shared__ float hs[16][260];
    __shared__ float gsh[32][16];

    // preload weight slice (once)
    {
        const float4* src = (const float4*)(W + (size_t)grow * 256 + rem * 8);
        *(float4*)&Ws[r][rem * 8]     = src[0];
        *(float4*)&Ws[r][rem * 8 + 4] = src[1];
    }
    // init h buffer 0
    float c = 0.f, hn = 0.f;
    if (tid < 128) {
        int ju2 = tid >> 4, b2 = tid & 15;
        atomicExch(&hg[dir * 4096 + b2 * 256 + q * 8 + ju2], 0.f);
    }
    gbar(cnt, gen, 64, 1);

    int cur = 0;
    for (int step = 0; step < S_LEN; step++) {
        int t = dir ? (S_LEN - 1 - step) : step;
        // stage h(t) into LDS (device-coherent atomic reads)
        {
            int idx = tid * 4;
            int b3 = idx >> 8, k3 = idx & 255;
            float* src = &hg[cur * 8192 + dir * 4096 + b3 * 256 + k3];
            hs[b3][k3 + 0] = atomicAdd(&src[0], 0.f);
            hs[b3][k3 + 1] = atomicAdd(&src[1], 0.f);
            hs[b3][k3 + 2] = atomicAdd(&src[2], 0.f);
            hs[b3][k3 + 3] = atomicAdd(&src[3], 0.f);
        }
        __syncthreads();
        // half-dot + pair combine
        {
            const float4* wrow = (const float4*)&Ws[r][kh * 128];
            const float4* hrow = (const float4*)&hs[b][kh * 128];
            float s = 0.f;
#pragma unroll 8
            for (int k4 = 0; k4 < 32; k4++) {
                float4 w = wrow[k4], v = hrow[k4];
                s += w.x * v.x + w.y * v.y + w.z * v.z + w.w * v.w;
            }
            s += __shfl_xor(s, 1);
            if (kh == 0) gsh[r][b] = s + gx[((size_t)t * 16 + b) * 1024 + grow];
        }
        __syncthreads();
        // cell update for owned units
        if (tid < 128) {
            int ju2 = tid >> 4, b2 = tid & 15;
            float gi = gsh[ju2][b2],      gf = gsh[8 + ju2][b2];
            float gg = gsh[16 + ju2][b2], go = gsh[24 + ju2][b2];
            float i = sigm(gi), f = sigm(gf), g2 = tanhf(gg), o = sigm(go);
            c = f * c + i * g2;
            hn = o * tanhf(c);
            int unit = q * 8 + ju2;
            y[((size_t)t * 16 + b2) * 512 + dir * 256 + unit] = hn;
            atomicExch(&hg[(cur ^ 1) * 8192 + dir * 4096 + b2 * 256 + unit], hn);
        }
        gbar(cnt, gen, 64, step + 2);
        cur ^= 1;
    }
    if (hbO && dir == 1 && tid < 128) {
        int ju2 = tid >> 4, b2 = tid & 15;
        hbO[b2 * 256 + q * 8 + ju2] = hn;
        cbO[b2 * 256 + q * 8 + ju2] = c;
    }
}

// ---------------- decoder prologue: state init + qW0. grid 16 x 256.
__global__ __launch_bounds__(256) void d_init(
    const float* __restrict__ x, const float* __restrict__ u,
    const float* __restrict__ hb, const float* __restrict__ cb,
    const float* __restrict__ pWaT,
    float* __restrict__ dh0, float* __restrict__ dc0,
    float* __restrict__ dh1, float* __restrict__ dc1,
    float* __restrict__ ddin, float* __restrict__ dqW)
{
    int b = blockIdx.x, tid = threadIdx.x;
    __shared__ float h1s[256];
    float hv = hb[b * 256 + tid], cv = cb[b * 256 + tid];
    dh0[b * 256 + tid] = hv; dh1[b * 256 + tid] = hv;
    dc0[b * 256 + tid] = cv; dc1[b * 256 + tid] = cv;
    h1s[tid] = hv;
    if (tid < 16) ddin[b * 24 + tid] = x[((size_t)b * S_LEN + (S_LEN - 1)) * 16 + tid];
    else if (tid < 24) ddin[b * 24 + tid] = u[((size_t)b * S_LEN + (S_LEN - 1)) * 8 + (tid - 16)];
    __syncthreads();
    float s = 0.f;
    for (int k = 0; k < 256; k++) s += h1s[k] * pWaT[k * 256 + tid];
    dqW[b * 256 + tid] = s;
}

// ---------------- attention scan: grid (16,8) x 256.
__global__ __launch_bounds__(256) void d_attn(
    const float* __restrict__ Ept, const float* __restrict__ enc,
    const float* __restrict__ dqW, const float* __restrict__ va,
    float* __restrict__ de, float* __restrict__ dpsum, float* __restrict__ dpctx)
{
    int b = blockIdx.x, sc = blockIdx.y, tid = threadIdx.x;
    int sl = tid & 63, q = tid >> 6;
    __shared__ float qWs[256], vsh[256], red[256], esh[64];
    qWs[tid] = dqW[b * 256 + tid];
    vsh[tid] = va[tid];
    __syncthreads();
    const float* ep = Ept + (((size_t)(b * 256 + q * 64)) << 9) + sc * 64 + sl;
    float part = 0.f;
#pragma unroll 8
    for (int m = 0; m < 64; m++)
        part += tanhf(ep[(size_t)m << 9] + qWs[q * 64 + m]) * vsh[q * 64 + m];
    red[tid] = part;
    __syncthreads();
    if (q == 0) {
        float a = red[sl] + red[64 + sl] + red[128 + sl] + red[192 + sl];
        float e = expf(a);               // no max-sub: |alpha| <= sum|va| ~ 10
        esh[sl] = e;
        de[b * 512 + sc * 64 + sl] = e;
    }
    __syncthreads();
    if (tid == 0) {
        float s = 0.f;
        for (int i = 0; i < 64; i++) s += esh[i];
        dpsum[b * 8 + sc] = s;
    }
    float cp = 0.f;
#pragma unroll 4
    for (int s1 = 0; s1 < 64; s1++)
        cp += esh[s1] * enc[((size_t)((sc * 64 + s1) * BATCH + b) << 8) + tid];
    dpctx[((b * 8 + sc) << 8) + tid] = cp;
}

// ---------------- sequential core: grid 16 x 1024.
__global__ __launch_bounds__(1024) void d_step(
    const float* __restrict__ de, const float* __restrict__ dpsum,
    const float* __restrict__ dpctx,
    float* __restrict__ ddin, float* __restrict__ dh0, float* __restrict__ dc0,
    float* __restrict__ dh1, float* __restrict__ dc1, float* __restrict__ dqW,
    const float* __restrict__ pdWih0, const float* __restrict__ pdWhh0,
    const float* __restrict__ dbih0, const float* __restrict__ dbhh0,
    const float* __restrict__ pdWih1, const float* __restrict__ pdWhh1,
    const float* __restrict__ dbih1, const float* __restrict__ dbhh1,
    const float* __restrict__ pWo1T, const float* __restrict__ bo1,
    const float* __restrict__ Wo2, const float* __restrict__ bo2,
    const float* __restrict__ pWaT, int t, float* __restrict__ outp)
{
    int b = blockIdx.x, tid = threadIdx.x;
    __shared__ __align__(16) float din[280];
    __shared__ __align__(16) float h0s[256], h1s[256];
    __shared__ float comb[1024], r1[256];
    __shared__ float Sig;
    float c0r = 0.f, c1r = 0.f;
    if (tid < 256) {
        h0s[tid] = dh0[b * 256 + tid]; h1s[tid] = dh1[b * 256 + tid];
        c0r = dc0[b * 256 + tid]; c1r = dc1[b * 256 + tid];
    }
    if (tid < 24) din[tid] = ddin[b * 24 + tid];
    if (tid == 0) {
        float s = 0.f;
        const float* ps = dpsum + b * 8;
        for (int i = 0; i < 8; i++) s += ps[i];
        Sig = s;
    }
    __syncthreads();
    float inv = 1.f / Sig;
    if (tid < 512)
        outp[6144 + ((size_t)(b * T_LEN + t)) * 512 + tid] = de[b * 512 + tid] * inv;
    if (tid < 256) {
        float s = 0.f;
        for (int sc = 0; sc < 8; sc++) s += dpctx[((b * 8 + sc) << 8) + tid];
        din[24 + tid] = s * inv;
    }
    __syncthreads();
    // cell0
    {
        const float4* wi = (const float4*)pdWih0;
        const float4* wh = (const float4*)pdWhh0;
        const float4* d4 = (const float4*)din;
        const float4* h4 = (const float4*)h0s;
        float s = dbih0[tid] + dbhh0[tid];
#pragma unroll 2
        for (int k4 = 0; k4 < 70; k4++) { float4 w = wi[k4 * 1024 + tid]; float4 v = d4[k4]; s += w.x*v.x + w.y*v.y + w.z*v.z + w.w*v.w; }
#pragma unroll 2
        for (int k4 = 0; k4 < 64; k4++) { float4 w = wh[k4 * 1024 + tid]; float4 v = h4[k4]; s += w.x*v.x + w.y*v.y + w.z*v.z + w.w*v.w; }
        comb[tid] = s;
    }
    __syncthreads();
    if (tid < 256) {
        float i = sigm(comb[tid]), f = sigm(comb[256 + tid]);
        float gg = tanhf(comb[512 + tid]), o = sigm(comb[768 + tid]);
        float c = f * c0r + i * gg;
        dc0[b * 256 + tid] = c;
        float hn = o * tanhf(c);
        h0s[tid] = hn; dh0[b * 256 + tid] = hn;
    }
    __syncthreads();
    // cell1
    {
        const float4* wi = (const float4*)pdWih1;
        const float4* wh = (const float4*)pdWhh1;
        const float4* a4 = (const float4*)h0s;
        const float4* h4 = (const float4*)h1s;
        float s = dbih1[tid] + dbhh1[tid];
#pragma unroll 2
        for (int k4 = 0; k4 < 64; k4++) { float4 w = wi[k4 * 1024 + tid]; float4 v = a4[k4]; s += w.x*v.x + w.y*v.y + w.z*v.z + w.w*v.w; }
#pragma unroll 2
        for (int k4 = 0; k4 < 64; k4++) { float4 w = wh[k4 * 1024 + tid]; float4 v = h4[k4]; s += w.x*v.x + w.y*v.y + w.z*v.z + w.w*v.w; }
        comb[tid] = s;
    }
    __syncthreads();
    if (tid < 256) {
        float i = sigm(comb[tid]), f = sigm(comb[256 + tid]);
        float gg = tanhf(comb[512 + tid]), o = sigm(comb[768 + tid]);
        float c = f * c1r + i * gg;
        dc1[b * 256 + tid] = c;
        float hn = o * tanhf(c);
        h1s[tid] = hn; dh1[b * 256 + tid] = hn;
    }
    __syncthreads();
    // out projection
    {
        int o = tid & 255, q = tid >> 8;
        float s = 0.f;
        for (int k = q * 64; k < q * 64 + 64; k++) s += h1s[k] * pWo1T[k * 256 + o];
        comb[tid] = s;
    }
    __syncthreads();
    if (tid < 256) r1[tid] = fmaxf(bo1[tid] + comb[tid] + comb[256 + tid] + comb[512 + tid] + comb[768 + tid], 0.f);
    __syncthreads();
    if (tid < 256) {
        int o = tid >> 5, l = tid & 31;
        const float* wr = Wo2 + (size_t)o * 256;
        float s = 0.f;
#pragma unroll
        for (int m = 0; m < 8; m++) { int k = l + m * 32; s += r1[k] * wr[k]; }
        comb[tid] = s;
    }
    __syncthreads();
    if (tid < 8) {
        float s = bo2[tid];
        for (int l = 0; l < 32; l++) s += comb[tid * 32 + l];
        outp[((size_t)(b * T_LEN + t)) * 8 + tid] = s;
        ddin[b * 24 + 16 + tid] = s;
    }
    __syncthreads();
    // next-step qW
    {
        int n = tid & 255, q = tid >> 8;
        float s = 0.f;
        for (int k = q * 64; k < q * 64 + 64; k++) s += h1s[k] * pWaT[k * 256 + n];
        comb[tid] = s;
    }
    __syncthreads();
    if (tid < 256) dqW[b * 256 + tid] = comb[tid] + comb[256 + tid] + comb[512 + tid] + comb[768 + tid];
}

extern "C" void kernel_launch(void* const* d_in, const int* in_sizes, int n_in,
                              void* d_out, int out_size, void* d_ws, size_t ws_size,
                              hipStream_t stream) {
    static const int kExp[36] = {
        131072, 65536, 1,
        24576, 262144, 1024, 1024,
        24576, 262144, 1024, 1024,
        524288, 262144, 1024, 1024,
        524288, 262144, 1024, 1024,
        131072, 256,
        286720, 262144, 1024, 1024,
        262144, 262144, 1024, 1024,
        131072, 256, 256,
        65536, 256, 2048, 8
    };
    bool ok = (n_in == 36);
    if (ok) for (int i = 0; i < 36; i++) if (in_sizes[i] != kExp[i]) { ok = false; break; }
    if (!ok) { k_guard<<<(out_size + 255) / 256, 256, 0, stream>>>((float*)d_out, out_size, 0.05f); return; }
    if (out_size != 399360) { k_guard<<<(out_size + 255) / 256, 256, 0, stream>>>((float*)d_out, out_size, 0.07f); return; }
    if (ws_size < WS_NEED_BYTES) {
        float v = (float)(ws_size >> 20) * 1e-4f;
        k_guard<<<(out_size + 255) / 256, 256, 0, stream>>>((float*)d_out, out_size, v);
        return;
    }

    const float* x       = (const float*)d_in[0];
    const float* u       = (const float*)d_in[1];
    const float* eWih_f0 = (const float*)d_in[3];
    const float* eWhh_f0 = (const float*)d_in[4];
    const float* ebih_f0 = (const float*)d_in[5];
    const float* ebhh_f0 = (const float*)d_in[6];
    const float* eWih_b0 = (const float*)d_in[7];
    const float* eWhh_b0 = (const float*)d_in[8];
    const float* ebih_b0 = (const float*)d_in[9];
    const float* ebhh_b0 = (const float*)d_in[10];
    const float* eWih_f1 = (const float*)d_in[11];
    const float* eWhh_f1 = (const float*)d_in[12];
    const float* ebih_f1 = (const float*)d_in[13];
    const float* ebhh_f1 = (const float*)d_in[14];
    const float* eWih_b1 = (const float*)d_in[15];
    const float* eWhh_b1 = (const float*)d_in[16];
    const float* ebih_b1 = (const float*)d_in[17];
    const float* ebhh_b1 = (const float*)d_in[18];
    const float* Wp      = (const float*)d_in[19];
    const float* bp      = (const float*)d_in[20];
    const float* dWih0   = (const float*)d_in[21];
    const float* dWhh0   = (const float*)d_in[22];
    const float* dbih0   = (const float*)d_in[23];
    const float* dbhh0   = (const float*)d_in[24];
    const float* dWih1   = (const float*)d_in[25];
    const float* dWhh1   = (const float*)d_in[26];
    const float* dbih1   = (const float*)d_in[27];
    const float* dbhh1   = (const float*)d_in[28];
    const float* Wa      = (const float*)d_in[29];
    const float* ba      = (const float*)d_in[30];
    const float* va      = (const float*)d_in[31];
    const float* Wo1     = (const float*)d_in[32];
    const float* bo1     = (const float*)d_in[33];
    const float* Wo2     = (const float*)d_in[34];
    const float* bo2     = (const float*)d_in[35];

    float* ws = (float*)d_ws;
    float* A      = ws;
    float* enc    = ws;
    float* EpTmp  = ws + 2097152;
    float* Ept    = ws + 4194304;
    float* dh0    = ws + 12582912;
    float* dc0    = ws + 12587008;
    float* dh1    = ws + 12591104;
    float* dc1    = ws + 12595200;
    float* ddin   = ws + 12599296;
    float* dqW    = ws + 12599808;
    float* de     = ws + 12603904;
    float* dpsum  = ws + 12612096;
    float* dpctx  = ws + 12612224;
    float* hg     = ws + 12645376;       // 16384
    int*   syncp  = (int*)(ws + 12661760);
    float* y      = ws + 16777216;
    float* hb     = ws + 20971520;
    float* cb     = ws + 20975616;
    float* inp    = ws + 20979712;
    float* pdWih0 = ws + 22224896;
    float* pdWhh0 = ws + 22511616;
    float* pdWih1 = ws + 22773760;
    float* pdWhh1 = ws + 23035904;
    float* pWo1T  = ws + 23298048;
    float* pWaT   = ws + 23363584;

    // packing (decoder only; recurrence reads raw Whh)
    k_inp<<<768, 256, 0, stream>>>(x, u, inp);
    k_pack4<<<1120, 256, 0, stream>>>(dWih0, pdWih0, 280);
    k_pack4<<<1024, 256, 0, stream>>>(dWhh0, pdWhh0, 256);
    k_pack4<<<1024, 256, 0, stream>>>(dWih1, pdWih1, 256);
    k_pack4<<<1024, 256, 0, stream>>>(dWhh1, pdWhh1, 256);
    k_trT<<<256, 256, 0, stream>>>(Wa, 512, pWaT);
    k_trT<<<256, 256, 0, stream>>>(Wo1, 256, pWo1T);

    // encoder layer 0
    k_ngemm<<<32768, 256, 0, stream>>>(inp, 24, eWih_f0, 24, ebih_f0, ebhh_f0, A, 8192, 1024, 24);
    k_ngemm<<<32768, 256, 0, stream>>>(inp, 24, eWih_b0, 24, ebih_b0, ebhh_b0, A + 8388608, 8192, 1024, 24);
    hipMemsetAsync(syncp, 0, 8, stream);
    k_recP<<<dim3(32, 2), 1024, 0, stream>>>(A, eWhh_f0, eWhh_b0, y, hg, syncp, nullptr, nullptr);
    // encoder layer 1
    k_gemm<<<dim3(128, 16), 256, 0, stream>>>(y, 512, eWih_f1, 512, 0, ebih_f1, ebhh_f1, A, 1024, 512);
    k_gemm<<<dim3(128, 16), 256, 0, stream>>>(y, 512, eWih_b1, 512, 0, ebih_b1, ebhh_b1, A + 8388608, 1024, 512);
    hipMemsetAsync(syncp, 0, 8, stream);
    k_recP<<<dim3(32, 2), 1024, 0, stream>>>(A, eWhh_f1, eWhh_b1, y, hg, syncp, hb, cb);
    // enc projection + attention precompute
    k_gemm<<<dim3(128, 4), 256, 0, stream>>>(y, 512, Wp, 512, 0, bp, nullptr, enc, 256, 512);
    k_gemm<<<dim3(128, 4), 256, 0, stream>>>(enc, 256, Wa, 512, 256, ba, nullptr, EpTmp, 256, 256);
    k_trEp<<<8192, 256, 0, stream>>>(EpTmp, Ept);

    // decoder
    d_init<<<16, 256, 0, stream>>>(x, u, hb, cb, pWaT, dh0, dc0, dh1, dc1, ddin, dqW);
    for (int t = 0; t < T_LEN; t++) {
        d_attn<<<dim3(16, 8), 256, 0, stream>>>(Ept, enc, dqW, va, de, dpsum, dpctx);
        d_step<<<16, 1024, 0, stream>>>(de, dpsum, dpctx, ddin, dh0, dc0, dh1, dc1, dqW,
                                        pdWih0, pdWhh0, dbih0, dbhh0,
                                        pdWih1, pdWhh1, dbih1, dbhh1,
                                        pWo1T, bo1, Wo2, bo2, pWaT, t, (float*)d_out);
    }
}